// Round 2
// baseline (553.306 us; speedup 1.0000x reference)
//
#include <hip/hip_runtime.h>
#include <hip/hip_fp16.h>

// DySample fused kernel for MI355X (gfx950) — round 5.
// x: [16,64,128,128] f32, w_off: [32,64] f32, b_off: [32] f32
// out: [16,64,256,256] f32
//
// r3 (152 us kernel) was HBM-byte-bound (~1 GB moved vs ~330 MB necessary);
// r4's LDS staging broke latency hiding (232 us, 53% BW). r5 returns to the
// barrier-free gather skeleton and cuts bytes:
//  - quad-sharing: 1 thread = 1 input px = 2x2 output quad; 4 samples share
//    one 3x3 neighborhood (9 loads vs 16). Border-exact via folded weights
//    (zero-weight taps), selects hoisted out of the channel loop.
//  - twin blocks remapped (gg = blockIdx>>10) so a pair lands on the SAME
//    XCD (+1024 = 0 mod 8) and shares L2 lines -> no double HBM fetch.
//  - plain float2 stores (NT showed 1.6x write amplification: 408 MiB for a
//    256 MiB output).
// Generic global-gather fallback per gi (valid flag) keeps large offsets
// correct; execz-skipped for this input (|off| <= ~0.27).

namespace {
constexpr int CC = 64;
constexpr int HH = 128;
constexpr int WW = 128;
constexpr int HW = HH * WW;     // 16384
constexpr int OW = 2 * WW;      // 256
constexpr int OHW = 4 * HW;     // 65536
constexpr int TH = 8, TW = 32;  // input tile (256 px)
typedef float vfloat2 __attribute__((ext_vector_type(2)));
}

__global__ __launch_bounds__(256, 8)
void dysample_kernel(const float* __restrict__ x,
                     const float* __restrict__ w_off,
                     const float* __restrict__ b_off,
                     float* __restrict__ out) {
    __shared__ __half2 offh[8][256];   // 8 KB: (offx,offy) per local-q per pixel

    const int tid  = threadIdx.x;
    const int gg   = blockIdx.x >> 10;        // twin id: pair (k, k+1024) -> same XCD
    const int rest = blockIdx.x & 1023;
    const int tile = rest & 63;
    const int b    = rest >> 6;
    const int th0  = (tile >> 2) * TH;
    const int tw0  = (tile & 3) * TW;
    const int ty   = tid >> 5;                // [0,8)
    const int tx   = tid & 31;                // [0,32)
    const int h    = th0 + ty;
    const int w    = tw0 + tx;
    const int q0   = gg * 8;                  // first of 8 q-channels (x half)

    // ---------- Phase 1: 1x1 conv, 16 of 32 outputs at this thread's pixel ----
    // (verbatim from the verified r3 kernel)
    {
        float accx[8], accy[8];
#pragma unroll
        for (int j = 0; j < 8; ++j) {
            accx[j] = b_off[q0 + j];
            accy[j] = b_off[q0 + j + 16];
        }

        const float* xb = x + b * (CC * HW) + h * WW + w;
#pragma unroll
        for (int chunk = 0; chunk < 4; ++chunk) {
            float xv[16];
#pragma unroll
            for (int c = 0; c < 16; ++c) xv[c] = xb[(chunk * 16 + c) * HW];
#pragma unroll
            for (int j = 0; j < 8; ++j) {
                float ax = accx[j], ay = accy[j];
                const float* wx_ = w_off + (q0 + j) * 64 + chunk * 16;
                const float* wy_ = wx_ + 16 * 64;
#pragma unroll
                for (int c = 0; c < 16; ++c) ax = fmaf(xv[c], wx_[c], ax);
#pragma unroll
                for (int c = 0; c < 16; ++c) ay = fmaf(xv[c], wy_[c], ay);
                accx[j] = ax; accy[j] = ay;
            }
        }

#pragma unroll
        for (int j = 0; j < 8; ++j) {
            const int q = q0 + j, g = q >> 2, r1_ = (q >> 1) & 1, r2_ = q & 1;
            const float init = (((g & 1) ? r1_ : r2_) ? 0.25f : -0.25f);
            const float offx = fmaf(accx[j], 0.25f, init);
            const float offy = fmaf(accy[j], 0.25f, init);
            offh[j][tid] = __floats2half2_rn(offx, offy);
        }
    }
    __syncthreads();

    // ---------- Phase 2: quad sampling, 9-tap shared 3x3 neighborhood --------
    const int rm  = max(h - 1, 0) * WW;
    const int r0_ = h * WW;
    const int rp  = min(h + 1, HH - 1) * WW;
    const int cm  = max(w - 1, 0);
    const int cp  = min(w + 1, WW - 1);
    const int a0 = rm + cm,  a1 = rm + w,  a2 = rm + cp;
    const int a3 = r0_ + cm, a4 = r0_ + w, a5 = r0_ + cp;
    const int a6 = rp + cm,  a7 = rp + w,  a8 = rp + cp;
    const float fw = (float)w, fh = (float)h;

    const float* xgg = x + (size_t)(b * CC + gg * 32) * HW;
    float* ogg = out + (size_t)(b * CC + gg * 32) * OHW
               + (size_t)(2 * h) * OW + 2 * w;

#pragma unroll
    for (int gi = 0; gi < 2; ++gi) {
        // Per-q folded 3-tap weights (selects hoisted out of the c-loop).
        float wcq[4][3], wrq[4][3];
        bool vall = true;
#pragma unroll
        for (int p = 0; p < 4; ++p) {          // p = 2*r1 + r2
            const float2 o = __half22float2(offh[gi * 4 + p][tid]);
            float ix = ((fw + 0.5f) + o.x) - 0.5f;
            float iy = ((fh + 0.5f) + o.y) - 0.5f;
            ix = fminf(fmaxf(ix, 0.0f), 127.0f);
            iy = fminf(fmaxf(iy, 0.0f), 127.0f);
            const float x0f = floorf(ix), y0f = floorf(iy);
            const float wx = ix - x0f, wy = iy - y0f;
            const int sx = (int)x0f - (w - 1);  // 0: taps {w-1,w}; 1: {w,w+1}
            const int sy = (int)y0f - (h - 1);
            vall = vall && ((unsigned)sx <= 1u) && ((unsigned)sy <= 1u);
            const bool bx = (sx != 0), by = (sy != 0);
            wcq[p][0] = bx ? 0.0f : 1.0f - wx;
            wcq[p][1] = bx ? 1.0f - wx : wx;
            wcq[p][2] = bx ? wx : 0.0f;
            wrq[p][0] = by ? 0.0f : 1.0f - wy;
            wrq[p][1] = by ? 1.0f - wy : wy;
            wrq[p][2] = by ? wy : 0.0f;
        }

        const float* xg = xgg + (size_t)(gi * 16) * HW;
        float* og = ogg + (size_t)(gi * 16) * OHW;

        if (vall) {
#pragma unroll 2
            for (int c = 0; c < 16; ++c) {
                const float* xs = xg + c * HW;
                const float m0 = xs[a0], m1 = xs[a1], m2 = xs[a2];
                const float m3 = xs[a3], m4 = xs[a4], m5 = xs[a5];
                const float m6 = xs[a6], m7 = xs[a7], m8 = xs[a8];
                float res[4];
#pragma unroll
                for (int p = 0; p < 4; ++p) {
                    const float rd0 = fmaf(wcq[p][2], m2,
                                      fmaf(wcq[p][1], m1, wcq[p][0] * m0));
                    const float rd1 = fmaf(wcq[p][2], m5,
                                      fmaf(wcq[p][1], m4, wcq[p][0] * m3));
                    const float rd2 = fmaf(wcq[p][2], m8,
                                      fmaf(wcq[p][1], m7, wcq[p][0] * m6));
                    res[p] = fmaf(wrq[p][2], rd2,
                             fmaf(wrq[p][1], rd1, wrq[p][0] * rd0));
                }
                vfloat2 lo, hi;
                lo.x = res[0]; lo.y = res[1];
                hi.x = res[2]; hi.y = res[3];
                *(vfloat2*)(og + (size_t)c * OHW) = lo;
                *(vfloat2*)(og + (size_t)c * OHW + OW) = hi;
            }
        } else {
            // Generic fallback: full border-clamped gather (cold; execz-skipped
            // for this input). Keeps arbitrary offsets correct.
            for (int c = 0; c < 16; ++c) {
                const float* xs = xg + c * HW;
#pragma unroll
                for (int p = 0; p < 4; ++p) {
                    const float2 o = __half22float2(offh[gi * 4 + p][tid]);
                    float ix = ((fw + 0.5f) + o.x) - 0.5f;
                    float iy = ((fh + 0.5f) + o.y) - 0.5f;
                    ix = fminf(fmaxf(ix, 0.0f), 127.0f);
                    iy = fminf(fmaxf(iy, 0.0f), 127.0f);
                    const float x0f = floorf(ix), y0f = floorf(iy);
                    const float wx = ix - x0f, wy = iy - y0f;
                    const int xa = (int)x0f, ya = (int)y0f;
                    const int xb2 = min(xa + 1, WW - 1);
                    const int yb2 = min(ya + 1, HH - 1);
                    const float v00 = xs[ya * WW + xa],  v01 = xs[ya * WW + xb2];
                    const float v10 = xs[yb2 * WW + xa], v11 = xs[yb2 * WW + xb2];
                    const float t = fmaf(wx, v01 - v00, v00);
                    const float u = fmaf(wx, v11 - v10, v10);
                    og[(size_t)c * OHW + (size_t)(p >> 1) * OW + (p & 1)] =
                        fmaf(wy, u - t, t);
                }
            }
        }
    }
}

extern "C" void kernel_launch(void* const* d_in, const int* in_sizes, int n_in,
                              void* d_out, int out_size, void* d_ws, size_t ws_size,
                              hipStream_t stream) {
    const float* x     = (const float*)d_in[0];
    const float* w_off = (const float*)d_in[1];
    const float* b_off = (const float*)d_in[2];
    float* out = (float*)d_out;
    (void)in_sizes; (void)n_in; (void)out_size; (void)d_ws; (void)ws_size;
    dysample_kernel<<<dim3(2048), dim3(256), 0, stream>>>(x, w_off, b_off, out);
}

// Round 3
// 388.123 us; speedup vs baseline: 1.4256x; 1.4256x over previous
//
#include <hip/hip_runtime.h>
#include <hip/hip_fp16.h>

// DySample fused kernel for MI355X (gfx950) — round 6.
// x: [16,64,128,128] f32, w_off: [32,64] f32, b_off: [32] f32
// out: [16,64,256,256] f32
//
// Structural dedup: ONE block per (b, 8x32 tile) does all 4 groups.
//  - Phase 1: thread = 1 input px; loads all 64 channels into regs (xv[64]);
//    x is fetched from HBM exactly once (64 MiB total). Conv computes all
//    32 offset channels (weights thread-uniform -> SGPR). Offsets kept in
//    regs as half2 (identical rounding to verified r3/r5).
//  - Phase 2 (per group g of 4): threads ds_write their own xv values into
//    a 10x36 LDS halo window (16 ch); only the 84-px halo ring comes from
//    global (prefetched one group ahead; barriers never gate on HBM).
//    Sampling = r5-verified folded-weight 3x3 quad; NT float2 stores
//    (plain stores measured WORSE: 630 vs 418 MiB write traffic).
//  - wg swizzle keeps spatially-adjacent tiles on one XCD (halo-line L2 hits).
// Generic global-gather fallback (per-thread valid flag) keeps arbitrary
// offsets correct; never taken for this input (|off| <= ~0.27).

namespace {
constexpr int CC = 64;
constexpr int HH = 128;
constexpr int WW = 128;
constexpr int HW = HH * WW;     // 16384
constexpr int OW = 2 * WW;      // 256
constexpr int OHW = 4 * HW;     // 65536
constexpr int TH = 8, TW = 32;  // input tile (256 px)
constexpr int WS = 36;          // LDS window row stride (floats)
constexpr int WPL = 10 * WS;    // 360 floats per channel plane
constexpr int RING = 84;        // halo ring px per channel (10x34 - 8x32)
typedef float vfloat2 __attribute__((ext_vector_type(2)));
}

__global__ __launch_bounds__(256, 2)
void dysample_kernel(const float* __restrict__ x,
                     const float* __restrict__ w_off,
                     const float* __restrict__ b_off,
                     float* __restrict__ out) {
    __shared__ float win[16][WPL];   // 23 KB: one group's halo windows

    const int tid  = threadIdx.x;
    // XCD-contiguous remap: blocks on one XCD cover 2 whole images.
    const int wg   = ((int)blockIdx.x & 7) * 128 + ((int)blockIdx.x >> 3);
    const int tile = wg & 63;
    const int b    = wg >> 6;
    const int th0  = (tile >> 2) * TH;
    const int tw0  = (tile & 3) * TW;
    const int ty   = tid >> 5;                // [0,8)
    const int tx   = tid & 31;                // [0,32)
    const int h    = th0 + ty;
    const int w    = tw0 + tx;

    // ---------- Phase 1: 1x1 conv, ALL 32 outputs at this thread's pixel ----
    float xv[64];
    __half2 offs[16];
    {
        float accx[16], accy[16];
#pragma unroll
        for (int j = 0; j < 16; ++j) {
            accx[j] = b_off[j];
            accy[j] = b_off[j + 16];
        }
        const float* xb = x + b * (CC * HW) + h * WW + w;
#pragma unroll
        for (int ch = 0; ch < 4; ++ch) {
#pragma unroll
            for (int c = 0; c < 16; ++c) xv[ch * 16 + c] = xb[(ch * 16 + c) * HW];
#pragma unroll
            for (int j = 0; j < 16; ++j) {
                float ax = accx[j], ay = accy[j];
                const float* wxp = w_off + j * 64 + ch * 16;
                const float* wyp = wxp + 16 * 64;
#pragma unroll
                for (int c = 0; c < 16; ++c) ax = fmaf(xv[ch * 16 + c], wxp[c], ax);
#pragma unroll
                for (int c = 0; c < 16; ++c) ay = fmaf(xv[ch * 16 + c], wyp[c], ay);
                accx[j] = ax; accy[j] = ay;
            }
        }
#pragma unroll
        for (int j = 0; j < 16; ++j) {
            const int g = j >> 2, r1_ = (j >> 1) & 1, r2_ = j & 1;
            const float init = (((g & 1) ? r1_ : r2_) ? 0.25f : -0.25f);
            offs[j] = __floats2half2_rn(fmaf(accx[j], 0.25f, init),
                                        fmaf(accy[j], 0.25f, init));
        }
    }

    // ---------- Halo-ring descriptors (84 px x 16 ch = 1344 slots) ----------
    int rsrc[6], rdst[6];
#pragma unroll
    for (int i = 0; i < 6; ++i) {
        const int s  = tid + 256 * i;
        const int ci = min(s / RING, 15);     // channel within group
        const int rp = s - ci * RING;
        int ry, rx;
        if (rp < 34)      { ry = 0;       rx = rp; }
        else if (rp < 68) { ry = 9;       rx = rp - 34; }
        else if (rp < 76) { ry = rp - 67; rx = 0; }
        else              { ry = rp - 75; rx = 33; }
        const int gr = min(max(th0 - 1 + ry, 0), HH - 1);
        const int gc = min(max(tw0 - 1 + rx, 0), WW - 1);
        rsrc[i] = ci * HW + gr * WW + gc;
        rdst[i] = ci * WPL + ry * WS + rx;
    }
    const bool v5 = (tid < 16 * RING - 5 * 256);  // tid < 64

    const float* xg0 = x + (size_t)b * (CC * HW);
    float ringv[6];
#pragma unroll
    for (int i = 0; i < 6; ++i)
        if (i < 5 || v5) ringv[i] = xg0[rsrc[i]];

    float* const ob = out + (size_t)b * (CC * OHW)
                    + (size_t)(2 * h) * OW + 2 * w;
    const float fw = (float)w, fh = (float)h;

    // ---------- Phase 2: per-group LDS window + folded-weight quad sampling --
#pragma unroll
    for (int g = 0; g < 4; ++g) {
        __syncthreads();                      // prev group's reads complete
#pragma unroll
        for (int ci = 0; ci < 16; ++ci)
            win[ci][(ty + 1) * WS + (tx + 1)] = xv[g * 16 + ci];
#pragma unroll
        for (int i = 0; i < 6; ++i)
            if (i < 5 || v5) (&win[0][0])[rdst[i]] = ringv[i];
        __syncthreads();
        if (g < 3) {                          // prefetch next group's ring
#pragma unroll
            for (int i = 0; i < 6; ++i)
                if (i < 5 || v5) ringv[i] = xg0[(g + 1) * (16 * HW) + rsrc[i]];
        }

        // Folded 3-tap weights for this group's 4 sub-pixels.
        float wc[4][3], wr[4][3];
        bool vall = true;
#pragma unroll
        for (int p = 0; p < 4; ++p) {         // p = 2*r1 + r2
            const float2 o = __half22float2(offs[g * 4 + p]);
            float ix = ((fw + 0.5f) + o.x) - 0.5f;
            float iy = ((fh + 0.5f) + o.y) - 0.5f;
            ix = fminf(fmaxf(ix, 0.0f), 127.0f);
            iy = fminf(fmaxf(iy, 0.0f), 127.0f);
            const float x0f = floorf(ix), y0f = floorf(iy);
            const float wxf = ix - x0f, wyf = iy - y0f;
            const int sx = (int)x0f - (w - 1);
            const int sy = (int)y0f - (h - 1);
            vall = vall && ((unsigned)sx <= 1u) && ((unsigned)sy <= 1u);
            const bool bx = (sx != 0), by = (sy != 0);
            wc[p][0] = bx ? 0.0f : 1.0f - wxf;
            wc[p][1] = bx ? 1.0f - wxf : wxf;
            wc[p][2] = bx ? wxf : 0.0f;
            wr[p][0] = by ? 0.0f : 1.0f - wyf;
            wr[p][1] = by ? 1.0f - wyf : wyf;
            wr[p][2] = by ? wyf : 0.0f;
        }

        float* const og = ob + (size_t)(g * 16) * OHW;
        if (vall) {
#pragma unroll 2
            for (int c = 0; c < 16; ++c) {
                const float* wp = &win[c][ty * WS + tx];
                const float m0 = wp[0],        m1 = wp[1],          m2 = wp[2];
                const float m3 = wp[WS],       m4 = wp[WS + 1],     m5 = wp[WS + 2];
                const float m6 = wp[2 * WS],   m7 = wp[2 * WS + 1], m8 = wp[2 * WS + 2];
                float res[4];
#pragma unroll
                for (int p = 0; p < 4; ++p) {
                    const float rd0 = fmaf(wc[p][2], m2,
                                      fmaf(wc[p][1], m1, wc[p][0] * m0));
                    const float rd1 = fmaf(wc[p][2], m5,
                                      fmaf(wc[p][1], m4, wc[p][0] * m3));
                    const float rd2 = fmaf(wc[p][2], m8,
                                      fmaf(wc[p][1], m7, wc[p][0] * m6));
                    res[p] = fmaf(wr[p][2], rd2,
                             fmaf(wr[p][1], rd1, wr[p][0] * rd0));
                }
                vfloat2 lo, hi;
                lo.x = res[0]; lo.y = res[1];
                hi.x = res[2]; hi.y = res[3];
                __builtin_nontemporal_store(lo, (vfloat2*)(og + (size_t)c * OHW));
                __builtin_nontemporal_store(hi, (vfloat2*)(og + (size_t)c * OHW + OW));
            }
        } else {
            // Generic fallback: border-clamped global gather (cold).
            for (int c = 0; c < 16; ++c) {
                const float* xs = xg0 + (size_t)(g * 16 + c) * HW;
#pragma unroll
                for (int p = 0; p < 4; ++p) {
                    const float2 o = __half22float2(offs[g * 4 + p]);
                    float ix = ((fw + 0.5f) + o.x) - 0.5f;
                    float iy = ((fh + 0.5f) + o.y) - 0.5f;
                    ix = fminf(fmaxf(ix, 0.0f), 127.0f);
                    iy = fminf(fmaxf(iy, 0.0f), 127.0f);
                    const float x0f = floorf(ix), y0f = floorf(iy);
                    const float wxf = ix - x0f, wyf = iy - y0f;
                    const int xa = (int)x0f, ya = (int)y0f;
                    const int xb2 = min(xa + 1, WW - 1);
                    const int yb2 = min(ya + 1, HH - 1);
                    const float v00 = xs[ya * WW + xa],  v01 = xs[ya * WW + xb2];
                    const float v10 = xs[yb2 * WW + xa], v11 = xs[yb2 * WW + xb2];
                    const float t = fmaf(wxf, v01 - v00, v00);
                    const float u = fmaf(wxf, v11 - v10, v10);
                    og[(size_t)c * OHW + (size_t)(p >> 1) * OW + (p & 1)] =
                        fmaf(wyf, u - t, t);
                }
            }
        }
    }
}

extern "C" void kernel_launch(void* const* d_in, const int* in_sizes, int n_in,
                              void* d_out, int out_size, void* d_ws, size_t ws_size,
                              hipStream_t stream) {
    const float* x     = (const float*)d_in[0];
    const float* w_off = (const float*)d_in[1];
    const float* b_off = (const float*)d_in[2];
    float* out = (float*)d_out;
    (void)in_sizes; (void)n_in; (void)out_size; (void)d_ws; (void)ws_size;
    dysample_kernel<<<dim3(1024), dim3(256), 0, stream>>>(x, w_off, b_off, out);
}

// Round 4
// 368.572 us; speedup vs baseline: 1.5012x; 1.0530x over previous
//
#include <hip/hip_runtime.h>
#include <hip/hip_fp16.h>

// DySample fused kernel for MI355X (gfx950) — round 7.
// x: [16,64,128,128] f32, w_off: [32,64] f32, b_off: [32] f32
// out: [16,64,256,256] f32
//
// r6 (~156 us) ran at ~50% achievable BW -> latency-bound, plus a persistent
// 1.6x NT write amplification on 256B-segment stores. r7:
//  - TH=2 x TW=128 full-width tiles: every NT float4 store inst covers one
//    full 1024B output row (stream-like writes, like the 1.0x-amp fills).
//  - 3 blocks/CU (launch_bounds(256,3); LDS 49 KB) for latency hiding.
//  - division-free halo ring: 2 full-width rows/plane, all 256 threads
//    coalesced; border cells are duplicates of already-loaded edge values.
//    Ring prefetched one group ahead into regs; barriers never gate on HBM.
// Conv order / half2 offset rounding / folded-weight fma association are
// verbatim from the verified r3/r5/r6 kernels (absmax unchanged).
// Generic global-gather fallback (per-group vall flag) keeps arbitrary
// offsets correct; execz-cold for this input (|off| <= ~0.27).

namespace {
constexpr int CC = 64;
constexpr int HH = 128;
constexpr int WW = 128;
constexpr int HW = HH * WW;     // 16384
constexpr int OW = 2 * WW;      // 256
constexpr int OHW = 4 * HW;     // 65536
constexpr int WS2 = 132;        // window row stride (floats)
constexpr int WPL2 = 4 * WS2;   // 528 floats per channel plane
typedef float vfloat4 __attribute__((ext_vector_type(4)));
}

__global__ __launch_bounds__(256, 3)
void dysample_kernel(const float* __restrict__ x,
                     const float* __restrict__ w_off,
                     const float* __restrict__ b_off,
                     float* __restrict__ out) {
    __shared__ __half2 offh[16][256];      // 16 KB: offsets per q per tile px
    __shared__ float   win[16 * WPL2];     // 33 KB: one group's 4x132 windows

    const int tid  = threadIdx.x;
    // XCD-contiguous remap: one XCD covers 2 whole images (vertical neighbors
    // share halo rows in its L2).
    const int wg   = ((int)blockIdx.x & 7) * 128 + ((int)blockIdx.x >> 3);
    const int tile = wg & 63;
    const int b    = wg >> 6;
    const int th0  = tile * 2;            // 2-row full-width band
    const int ty   = tid >> 7;            // [0,2)
    const int tx   = tid & 127;           // [0,128)

    const float* xg0 = x + (size_t)b * (CC * HW);

    // Ring descriptors (division-free): threads 0..127 -> window row 0
    // (input row th0-1), threads 128..255 -> window row 3 (input row th0+2).
    const int rrow  = th0 - 1 + ty * 3;
    const int grow  = min(max(rrow, 0), HH - 1);
    const int rsrc0 = grow * WW + tx;            // + c*HW per channel
    const int rdst0 = (ty * 3) * WS2 + (tx + 1); // + c*WPL2 per channel
    const bool e0   = (tx == 0);
    const bool e127 = (tx == 127);

    // ---------------- Phase 1: 1x1 conv (all 32 outputs) --------------------
    float xv[64];
    {
        float accx[16], accy[16];
#pragma unroll
        for (int j = 0; j < 16; ++j) {
            accx[j] = b_off[j];
            accy[j] = b_off[j + 16];
        }
        const float* xb = xg0 + (th0 + ty) * WW + tx;
#pragma unroll
        for (int ch = 0; ch < 4; ++ch) {
#pragma unroll
            for (int c = 0; c < 16; ++c) xv[ch * 16 + c] = xb[(ch * 16 + c) * HW];
#pragma unroll
            for (int j = 0; j < 16; ++j) {
                float ax = accx[j], ay = accy[j];
                const float* wxp = w_off + j * 64 + ch * 16;
                const float* wyp = wxp + 16 * 64;
#pragma unroll
                for (int c = 0; c < 16; ++c) ax = fmaf(xv[ch * 16 + c], wxp[c], ax);
#pragma unroll
                for (int c = 0; c < 16; ++c) ay = fmaf(xv[ch * 16 + c], wyp[c], ay);
                accx[j] = ax; accy[j] = ay;
            }
        }

        // Issue group-0 ring loads now: latency hides under offh/interior work.
        float ringv0[16];
#pragma unroll
        for (int c = 0; c < 16; ++c) ringv0[c] = xg0[c * HW + rsrc0];

#pragma unroll
        for (int j = 0; j < 16; ++j) {
            const int g = j >> 2, r1_ = (j >> 1) & 1, r2_ = j & 1;
            const float init = (((g & 1) ? r1_ : r2_) ? 0.25f : -0.25f);
            offh[j][ty * 128 + tx] = __floats2half2_rn(fmaf(accx[j], 0.25f, init),
                                                       fmaf(accy[j], 0.25f, init));
        }

        // Stage group 0: interior rows (own xv) + ring rows (ringv0).
#pragma unroll
        for (int c = 0; c < 16; ++c) {
            const int di = c * WPL2 + (1 + ty) * WS2 + (tx + 1);
            win[di] = xv[c];
            if (e0)   win[c * WPL2 + (1 + ty) * WS2 + 0]   = xv[c];
            if (e127) win[c * WPL2 + (1 + ty) * WS2 + 129] = xv[c];
        }
#pragma unroll
        for (int c = 0; c < 16; ++c) {
            win[c * WPL2 + rdst0] = ringv0[c];
            if (e0)   win[c * WPL2 + (ty * 3) * WS2 + 0]   = ringv0[c];
            if (e127) win[c * WPL2 + (ty * 3) * WS2 + 129] = ringv0[c];
        }
    }
    __syncthreads();

    // ---------------- Phase 2: per-group sampling ---------------------------
    const int oy  = tid >> 6;             // [0,4) output row within band
    const int x4  = tid & 63;             // float4 column group
    const int hl2 = oy >> 1;              // local input row [0,2)
    const int r1  = oy & 1;
    const int jb  = 2 * x4;               // window col base (taps jb..jb+3)
    const float fhh = (float)(th0 + hl2);
    float* const obase = out + (size_t)b * (CC * OHW)
                       + (size_t)(2 * th0 + oy) * OW + 4 * x4;

    float ringv[16];
#pragma unroll
    for (int g = 0; g < 4; ++g) {
        if (g < 3) {                       // prefetch next group's ring rows
#pragma unroll
            for (int c = 0; c < 16; ++c)
                ringv[c] = xg0[((g + 1) * 16 + c) * HW + rsrc0];
        }

        // Folded 3-tap weights for this group's 4 output px.
        float wcq[4][3], wrq[4][3];
        bool vall = true;
#pragma unroll
        for (int k = 0; k < 4; ++k) {
            const int q  = g * 4 + (r1 << 1) + (k & 1);
            const int wl = jb + (k >> 1);
            const float2 o = __half22float2(offh[q][hl2 * 128 + wl]);
            float ix = (((float)wl + 0.5f) + o.x) - 0.5f;
            float iy = ((fhh + 0.5f) + o.y) - 0.5f;
            ix = fminf(fmaxf(ix, 0.0f), 127.0f);
            iy = fminf(fmaxf(iy, 0.0f), 127.0f);
            const float x0f = floorf(ix), y0f = floorf(iy);
            const float wxf = ix - x0f, wyf = iy - y0f;
            const int sx = (int)x0f - (wl - 1);
            const int sy = (int)y0f - (th0 + hl2 - 1);
            vall = vall && ((unsigned)sx <= 1u) && ((unsigned)sy <= 1u);
            const bool bx = (sx != 0), by = (sy != 0);
            wcq[k][0] = bx ? 0.0f : 1.0f - wxf;
            wcq[k][1] = bx ? 1.0f - wxf : wxf;
            wcq[k][2] = bx ? wxf : 0.0f;
            wrq[k][0] = by ? 0.0f : 1.0f - wyf;
            wrq[k][1] = by ? 1.0f - wyf : wyf;
            wrq[k][2] = by ? wyf : 0.0f;
        }

        if (vall) {
#pragma unroll
            for (int c = 0; c < 16; ++c) {
                const float* wp = &win[c * WPL2 + hl2 * WS2 + jb];
                const float t00 = wp[0],           t01 = wp[1];
                const float t02 = wp[2],           t03 = wp[3];
                const float t10 = wp[WS2],         t11 = wp[WS2 + 1];
                const float t12 = wp[WS2 + 2],     t13 = wp[WS2 + 3];
                const float t20 = wp[2 * WS2],     t21 = wp[2 * WS2 + 1];
                const float t22 = wp[2 * WS2 + 2], t23 = wp[2 * WS2 + 3];
                vfloat4 res;
#pragma unroll
                for (int k = 0; k < 4; ++k) {
                    const float a0 = (k >> 1) ? t01 : t00;
                    const float a1 = (k >> 1) ? t02 : t01;
                    const float a2 = (k >> 1) ? t03 : t02;
                    const float b0 = (k >> 1) ? t11 : t10;
                    const float b1 = (k >> 1) ? t12 : t11;
                    const float b2 = (k >> 1) ? t13 : t12;
                    const float c0 = (k >> 1) ? t21 : t20;
                    const float c1 = (k >> 1) ? t22 : t21;
                    const float c2 = (k >> 1) ? t23 : t22;
                    const float rd0 = fmaf(wcq[k][2], a2,
                                      fmaf(wcq[k][1], a1, wcq[k][0] * a0));
                    const float rd1 = fmaf(wcq[k][2], b2,
                                      fmaf(wcq[k][1], b1, wcq[k][0] * b0));
                    const float rd2 = fmaf(wcq[k][2], c2,
                                      fmaf(wcq[k][1], c1, wcq[k][0] * c0));
                    res[k] = fmaf(wrq[k][2], rd2,
                             fmaf(wrq[k][1], rd1, wrq[k][0] * rd0));
                }
                __builtin_nontemporal_store(
                    res, (vfloat4*)(obase + (size_t)(g * 16 + c) * OHW));
            }
        } else {
            // Generic fallback: border-clamped global gather (cold).
            for (int c = 0; c < 16; ++c) {
                const float* xs = xg0 + (size_t)(g * 16 + c) * HW;
                float* og = obase + (size_t)(g * 16 + c) * OHW;
#pragma unroll
                for (int k = 0; k < 4; ++k) {
                    const int q  = g * 4 + (r1 << 1) + (k & 1);
                    const int wl = jb + (k >> 1);
                    const float2 o = __half22float2(offh[q][hl2 * 128 + wl]);
                    float ix = (((float)wl + 0.5f) + o.x) - 0.5f;
                    float iy = ((fhh + 0.5f) + o.y) - 0.5f;
                    ix = fminf(fmaxf(ix, 0.0f), 127.0f);
                    iy = fminf(fmaxf(iy, 0.0f), 127.0f);
                    const float x0f = floorf(ix), y0f = floorf(iy);
                    const float wxf = ix - x0f, wyf = iy - y0f;
                    const int xa = (int)x0f, ya = (int)y0f;
                    const int xb2 = min(xa + 1, WW - 1);
                    const int yb2 = min(ya + 1, HH - 1);
                    const float v00 = xs[ya * WW + xa],  v01 = xs[ya * WW + xb2];
                    const float v10 = xs[yb2 * WW + xa], v11 = xs[yb2 * WW + xb2];
                    const float t = fmaf(wxf, v01 - v00, v00);
                    const float u = fmaf(wxf, v11 - v10, v10);
                    og[k] = fmaf(wyf, u - t, t);
                }
            }
        }

        if (g < 3) {
            __syncthreads();               // all reads of win done
#pragma unroll
            for (int c = 0; c < 16; ++c) {
                const float v = xv[(g + 1) * 16 + c];
                win[c * WPL2 + (1 + ty) * WS2 + (tx + 1)] = v;
                if (e0)   win[c * WPL2 + (1 + ty) * WS2 + 0]   = v;
                if (e127) win[c * WPL2 + (1 + ty) * WS2 + 129] = v;
            }
#pragma unroll
            for (int c = 0; c < 16; ++c) {
                win[c * WPL2 + rdst0] = ringv[c];
                if (e0)   win[c * WPL2 + (ty * 3) * WS2 + 0]   = ringv[c];
                if (e127) win[c * WPL2 + (ty * 3) * WS2 + 129] = ringv[c];
            }
            __syncthreads();               // win ready for next group
        }
    }
}

extern "C" void kernel_launch(void* const* d_in, const int* in_sizes, int n_in,
                              void* d_out, int out_size, void* d_ws, size_t ws_size,
                              hipStream_t stream) {
    const float* x     = (const float*)d_in[0];
    const float* w_off = (const float*)d_in[1];
    const float* b_off = (const float*)d_in[2];
    float* out = (float*)d_out;
    (void)in_sizes; (void)n_in; (void)out_size; (void)d_ws; (void)ws_size;
    dysample_kernel<<<dim3(1024), dim3(256), 0, stream>>>(x, w_off, b_off, out);
}